// Round 3
// baseline (304.845 us; speedup 1.0000x reference)
//
#include <hip/hip_runtime.h>

// Conv1d: x (32, 64, 16384) f32, w (64, 64, 3) f32, bias (64) f32
// -> out (32, 64, 16382) f32, VALID, stride 1.
// GEMM view: out[co][n] = sum_kappa A[co][kappa] * B[kappa][n] + bias[co]
//   kappa = kk*64 + ci  (kk-major) so each 8-elem B fragment has uniform kk
//   and consecutive ci -> 8 coalesced global loads at stride L_IN.
// R3: no LDS at all. Weights pre-converted to bf16 kappa-layout in d_ws by a
// tiny prep kernel; A-frags read from global (24.6 KB -> L1-resident).
// k-loop reordered kk-innermost so x line reuse distance is 1 step (L1 hits).

typedef __bf16 bf16x8 __attribute__((ext_vector_type(8)));
typedef float f32x16 __attribute__((ext_vector_type(16)));

#define C_IN 64
#define C_OUT 64
#define L_IN 16384
#define L_OUT 16382
#define NT 256          // n-columns per block

__global__ void prep_w(const float* __restrict__ w, __bf16* __restrict__ wg) {
  int i = blockIdx.x * 256 + threadIdx.x;
  if (i < C_OUT * 192) {
    int co = i / 192;
    int r = i - co * 192;
    int ci = r / 3;
    int kk = r - ci * 3;
    wg[co * 192 + kk * 64 + ci] = (__bf16)w[i];
  }
}

__global__ __launch_bounds__(256, 4) void conv1d_mfma(
    const float* __restrict__ x, const __bf16* __restrict__ wg,
    const float* __restrict__ bias, float* __restrict__ out) {
  const int t = threadIdx.x;
  const int bx = blockIdx.x;
  const int b = bx >> 6;        // batch
  const int tile = bx & 63;     // l-tile
  const int l0 = tile * NT;

  const int lane = t & 63;
  const int wv = t >> 6;
  const int half = lane >> 5;   // k-half within fragment
  const int ln = lane & 31;
  const int kh = half * 8;
  const int n0 = wv * 64 + ln;
  const int l_a = l0 + n0;      // column for b0 fragments

  const float* xb = x + (size_t)b * (C_IN * L_IN);

  f32x16 acc00 = {}, acc01 = {}, acc10 = {}, acc11 = {};

#pragma unroll
  for (int g = 0; g < 4; ++g) {
#pragma unroll
    for (int kk = 0; kk < 3; ++kk) {
      const int s = kk * 4 + g;
      // A fragments from global bf16 (kappa-layout); 16B-aligned, L1-resident
      bf16x8 a0 = *(const bf16x8*)&wg[ln * 192 + s * 16 + kh];
      bf16x8 a1 = *(const bf16x8*)&wg[(32 + ln) * 192 + s * 16 + kh];

      // B fragments: kk uniform, ci consecutive; kk-innermost order means
      // the lines read here were read last iteration too -> L1 hit
      const int ci0 = 16 * g + kh;            // == (s*16+kh)&63
      const int p0 = min(l_a + kk, L_IN - 1); // clamped lanes feed unstored cols
      const int p1 = min(l_a + 32 + kk, L_IN - 1);
      const int base = ci0 * L_IN;
      bf16x8 b0, b1;
#pragma unroll
      for (int jj = 0; jj < 8; ++jj) {
        b0[jj] = (__bf16)xb[base + jj * L_IN + p0];
        b1[jj] = (__bf16)xb[base + jj * L_IN + p1];
      }
      acc00 = __builtin_amdgcn_mfma_f32_32x32x16_bf16(a0, b0, acc00, 0, 0, 0);
      acc01 = __builtin_amdgcn_mfma_f32_32x32x16_bf16(a0, b1, acc01, 0, 0, 0);
      acc10 = __builtin_amdgcn_mfma_f32_32x32x16_bf16(a1, b0, acc10, 0, 0, 0);
      acc11 = __builtin_amdgcn_mfma_f32_32x32x16_bf16(a1, b1, acc11, 0, 0, 0);
    }
  }

  // ---- epilogue: C/D layout col = lane&31, row = (r&3) + 8*(r>>2) + 4*half
  const int l_base = l0 + wv * 64 + ln;
  const bool full = (l0 + NT <= L_OUT);  // only last tile needs guards
  if (full) {
#pragma unroll
    for (int mt = 0; mt < 2; ++mt) {
#pragma unroll
      for (int r = 0; r < 16; ++r) {
        int co = mt * 32 + 4 * half + (r & 3) + 8 * (r >> 2);
        float bv = bias[co];               // 256 B, L1-cached
        size_t row = ((size_t)b * C_OUT + co) * (size_t)L_OUT;
        float v0 = (mt == 0 ? acc00[r] : acc10[r]) + bv;
        float v1 = (mt == 0 ? acc01[r] : acc11[r]) + bv;
        out[row + l_base] = v0;
        out[row + l_base + 32] = v1;
      }
    }
  } else {
#pragma unroll
    for (int mt = 0; mt < 2; ++mt) {
#pragma unroll
      for (int r = 0; r < 16; ++r) {
        int co = mt * 32 + 4 * half + (r & 3) + 8 * (r >> 2);
        float bv = bias[co];
        size_t row = ((size_t)b * C_OUT + co) * (size_t)L_OUT;
        float v0 = (mt == 0 ? acc00[r] : acc10[r]) + bv;
        float v1 = (mt == 0 ? acc01[r] : acc11[r]) + bv;
        if (l_base < L_OUT) out[row + l_base] = v0;
        if (l_base + 32 < L_OUT) out[row + l_base + 32] = v1;
      }
    }
  }
}

extern "C" void kernel_launch(void* const* d_in, const int* in_sizes, int n_in,
                              void* d_out, int out_size, void* d_ws, size_t ws_size,
                              hipStream_t stream) {
  const float* x = (const float*)d_in[0];
  const float* w = (const float*)d_in[1];
  const float* bias = (const float*)d_in[2];
  float* out = (float*)d_out;
  __bf16* wg = (__bf16*)d_ws;  // 64*192*2 = 24576 B of scratch

  prep_w<<<dim3(48), dim3(256), 0, stream>>>(w, wg);
  conv1d_mfma<<<dim3(32 * 64), dim3(256), 0, stream>>>(x, wg, bias, out);
}